// Round 5
// baseline (230.494 us; speedup 1.0000x reference)
//
#include <hip/hip_runtime.h>
#include <cstdint>
#include <cstddef>

#define D 128
#define SAME_W 0.3f
#define CROSS_W 1.0f
#define NSLICE 8    // dst slices ~ XCDs (blockIdx%8 heuristic)
#define CAP 64      // bucket capacity: degree ~ Poisson(16), P(any >= 64) ~ 1e-14
#define GEMM_BLOCKS 1024  // 4 blocks/CU: VGPR=128 (R2 profile) fits 16 waves/CU.
                          // Grid was the occupancy cap, NOT registers (R3's
                          // launch_bounds(,4) spilled; grid-only bump is safe).

using bf16x8 = __attribute__((ext_vector_type(8))) __bf16;
using f32x4  = __attribute__((ext_vector_type(4))) float;
using i32x4  = __attribute__((ext_vector_type(4))) int;
using u32x4  = __attribute__((ext_vector_type(4))) unsigned;

__device__ __forceinline__ unsigned bf16rne(float f) {
    unsigned u = __float_as_uint(f);
    return (u + 0x7FFFu + ((u >> 16) & 1u)) >> 16;   // round-to-nearest-even
}

// ============ fused preprocessing: fill | x-split | W-combine, one dispatch
// Fill blocks come FIRST so the blockIdx%8 -> XCD round-robin slice mapping
// is preserved.
__global__ __launch_bounds__(256) void k_pre(
    // fill
    const int* __restrict__ src, const int* __restrict__ dst,
    const float* __restrict__ ew, const int* __restrict__ cell_len,
    int* __restrict__ cnt, unsigned* __restrict__ meta, int E, int sliceLen,
    int nFill,
    // split: x -> bf16 hi/lo + packed fp8
    const float* __restrict__ xf, uint2* __restrict__ xh2,
    uint2* __restrict__ xl2, unsigned* __restrict__ xq, int nvec, int nSplit,
    // wcombine
    const float* __restrict__ W1, const float* __restrict__ W2,
    unsigned* __restrict__ wsh, unsigned* __restrict__ w12h,
    unsigned* __restrict__ w12l)
{
    const int b = blockIdx.x;
    if (b < nFill) {
        // ---- XCD-sliced capped-bucket fill. Non-temporal edge loads: the
        // streaming re-read must not evict the slice-local meta lines (1.6MB,
        // L2-resident per XCD) from L2.
        const int slice = b & (NSLICE - 1);
        const int lo = slice * sliceLen, hi = lo + sliceLen;
        const int chunk = b >> 3;                 // 2048 edges per chunk
        const int c = *cell_len;
        #pragma unroll
        for (int u = 0; u < 2; ++u) {
            const int e = chunk * 2048 + u * 1024 + (int)threadIdx.x * 4;
            if (e + 3 < E) {
                i32x4 d4 = __builtin_nontemporal_load((const i32x4*)(dst + e));
                i32x4 s4 = __builtin_nontemporal_load((const i32x4*)(src + e));
                f32x4 w4 = __builtin_nontemporal_load((const f32x4*)(ew + e));
                #pragma unroll
                for (int k = 0; k < 4; ++k) {
                    const int d = d4[k];
                    if (d >= lo && d < hi) {
                        const int   s = s4[k];
                        const float w = w4[k];
                        float wt = w * (((s > c) == (d > c)) ? SAME_W : CROSS_W);
                        int pos = atomicAdd(&cnt[d], 1);
                        if (pos < CAP)   // P(overflow) ~ 1e-14; guard for safety
                            meta[d * CAP + pos] = (unsigned)s | (bf16rne(wt) << 16);
                    }
                }
            } else {
                for (int k = 0; k < 4; ++k) {
                    const int ee = e + k;
                    if (ee < E) {
                        int d = __builtin_nontemporal_load(&dst[ee]);
                        if (d >= lo && d < hi) {
                            int s = __builtin_nontemporal_load(&src[ee]);
                            float w = __builtin_nontemporal_load(&ew[ee]);
                            float wt = w * (((s > c) == (d > c)) ? SAME_W : CROSS_W);
                            int pos = atomicAdd(&cnt[d], 1);
                            if (pos < CAP)
                                meta[d * CAP + pos] = (unsigned)s | (bf16rne(wt) << 16);
                        }
                    }
                }
            }
        }
    } else if (b < nFill + nSplit) {
        // ---- x -> split bf16 (hi+lo) + packed fp8 e4m3 (agg gather payload)
        int i = (b - nFill) * 256 + (int)threadIdx.x;
        if (i >= nvec) return;
        const f32x4* px = (const f32x4*)(xf + (size_t)i * 4);
        f32x4 v = __builtin_nontemporal_load(px);
        unsigned h0 = bf16rne(v[0]), h1 = bf16rne(v[1]),
                 h2 = bf16rne(v[2]), h3 = bf16rne(v[3]);
        xh2[i] = make_uint2(h0 | (h1 << 16), h2 | (h3 << 16));
        float r0 = v[0] - __uint_as_float(h0 << 16);
        float r1 = v[1] - __uint_as_float(h1 << 16);
        float r2 = v[2] - __uint_as_float(h2 << 16);
        float r3 = v[3] - __uint_as_float(h3 << 16);
        xl2[i] = make_uint2(bf16rne(r0) | (bf16rne(r1) << 16),
                            bf16rne(r2) | (bf16rne(r3) << 16));
        int q = __builtin_amdgcn_cvt_pk_fp8_f32(v[0], v[1], 0, false);
        q = __builtin_amdgcn_cvt_pk_fp8_f32(v[2], v[3], q, true);
        xq[i] = (unsigned)q;
    } else {
        // ---- Ws = bf16(W1+W2); W12 = split-bf16(W2 @ W1)
        // out = A2 + A1@Ws^T + x@W12^T (agg commutes with right-mul)
        int t = (b - nFill - nSplit) * 256 + threadIdx.x;
        int j = t >> 6, kp = t & 63;
        int k0 = kp * 2;
        float d0 = 0.f, d1 = 0.f;
        #pragma unroll 4
        for (int m = 0; m < D; ++m) {
            float a = W2[j * D + m];
            d0 = fmaf(a, W1[m * D + k0], d0);
            d1 = fmaf(a, W1[m * D + k0 + 1], d1);
        }
        float s0 = W1[j * D + k0] + W2[j * D + k0];
        float s1 = W1[j * D + k0 + 1] + W2[j * D + k0 + 1];
        wsh[j * 64 + kp] = bf16rne(s0) | (bf16rne(s1) << 16);
        unsigned h0 = bf16rne(d0), h1 = bf16rne(d1);
        w12h[j * 64 + kp] = h0 | (h1 << 16);
        float r0 = d0 - __uint_as_float(h0 << 16);
        float r1 = d1 - __uint_as_float(h1 << 16);
        w12l[j * 64 + kp] = bf16rne(r0) | (bf16rne(r1) << 16);
    }
}

// ---------------- gather + scatter-free mean over capped buckets, fp8 payload
// One wave per node; lane owns 2 features = 2 fp8 bytes (128B/row gather).
// HW v_cvt_f32_fp8 decode. uint4 meta loads; 16-deep unroll keeps 16
// independent row-gathers in flight. Outputs bf16-packed (GEMM A-operand /
// cin) and optionally fp8-packed (next agg's payload).
template <bool EMIT_FP8>
__global__ __launch_bounds__(256) void k_agg_fp8(const unsigned short* __restrict__ xq,
                                                 const uint4* __restrict__ meta4,
                                                 const int* __restrict__ cnt,
                                                 unsigned* __restrict__ outb,
                                                 unsigned short* __restrict__ outq,
                                                 int N) {
    int gid = blockIdx.x * blockDim.x + threadIdx.x;
    int node = gid >> 6;
    int lane = gid & 63;
    if (node >= N) return;
    const int cn0 = cnt[node];
    const int cn = min(cn0, CAP);
    const uint4* mrow = meta4 + (size_t)node * (CAP / 4);
    float ax0 = 0.f, ay0 = 0.f, ax1 = 0.f, ay1 = 0.f;
    int i = 0;
    #pragma unroll 1
    for (; i + 16 <= cn; i += 16) {
        uint4 mq[4];
        #pragma unroll
        for (int u = 0; u < 4; ++u) mq[u] = mrow[(i >> 2) + u];
        unsigned short v[16];
        #pragma unroll
        for (int u = 0; u < 16; ++u) {
            unsigned m = ((const unsigned*)mq)[u];
            v[u] = xq[(size_t)(m & 0xFFFFu) * 64 + lane];
        }
        #pragma unroll
        for (int u = 0; u < 16; ++u) {
            unsigned m = ((const unsigned*)mq)[u];
            float wt = __uint_as_float(m & 0xFFFF0000u);
            float vx = __builtin_amdgcn_cvt_f32_fp8((unsigned)v[u], 0);
            float vy = __builtin_amdgcn_cvt_f32_fp8((unsigned)v[u], 1);
            if (u & 1) { ax1 = fmaf(vx, wt, ax1); ay1 = fmaf(vy, wt, ay1); }
            else       { ax0 = fmaf(vx, wt, ax0); ay0 = fmaf(vy, wt, ay0); }
        }
    }
    #pragma unroll 1
    for (; i + 4 <= cn; i += 4) {
        uint4 mq = mrow[i >> 2];
        unsigned short v[4];
        #pragma unroll
        for (int u = 0; u < 4; ++u)
            v[u] = xq[(size_t)(((const unsigned*)&mq)[u] & 0xFFFFu) * 64 + lane];
        #pragma unroll
        for (int u = 0; u < 4; ++u) {
            unsigned m = ((const unsigned*)&mq)[u];
            float wt = __uint_as_float(m & 0xFFFF0000u);
            float vx = __builtin_amdgcn_cvt_f32_fp8((unsigned)v[u], 0);
            float vy = __builtin_amdgcn_cvt_f32_fp8((unsigned)v[u], 1);
            if (u & 1) { ax1 = fmaf(vx, wt, ax1); ay1 = fmaf(vy, wt, ay1); }
            else       { ax0 = fmaf(vx, wt, ax0); ay0 = fmaf(vy, wt, ay0); }
        }
    }
    for (; i < cn; ++i) {
        unsigned m = ((const unsigned*)mrow)[i];
        float wt = __uint_as_float(m & 0xFFFF0000u);
        unsigned short v = xq[(size_t)(m & 0xFFFFu) * 64 + lane];
        ax0 = fmaf(__builtin_amdgcn_cvt_f32_fp8((unsigned)v, 0), wt, ax0);
        ay0 = fmaf(__builtin_amdgcn_cvt_f32_fp8((unsigned)v, 1), wt, ay0);
    }
    const float scale = 1.0f / (float)max(cn0, 1);
    const float rx = (ax0 + ax1) * scale, ry = (ay0 + ay1) * scale;
    outb[(size_t)node * 64 + lane] = bf16rne(rx) | (bf16rne(ry) << 16);
    if (EMIT_FP8) {
        int q = __builtin_amdgcn_cvt_pk_fp8_f32(rx, ry, 0, false);
        outq[(size_t)node * 64 + lane] = (unsigned short)(q & 0xFFFF);
    }
}

// -------------- fused final GEMM: out = A2 + A1 @ Ws^T + x @ W12^T (split x)
// bf16 xh/xl loads (96B/lane-row, no cvt on the load->MFMA path).
// Persistent grid of 1024 = 4 blocks/CU at VGPR=128 (launch_bounds(256,2)
// keeps the allocator at 128 naturally — do NOT use min-waves=4, it spills,
// R3). Two A-fragment buffers ping-pong so tile t+1's loads fly during tile
// t's MFMAs.
__global__ __launch_bounds__(256, 2) void k_gemm2(
    const uint4* __restrict__ xh4, const uint4* __restrict__ xl4,   // [N][16]
    const uint4* __restrict__ a1h4,                                 // [N][16]
    const uint4* __restrict__ w12h4, const uint4* __restrict__ w12l4,
    const uint4* __restrict__ wsh4,                                 // [128][16]
    const unsigned* __restrict__ a2b,                               // [N][64] bf16x2
    float* __restrict__ fout, int N, int nTiles)
{
    const int t = threadIdx.x;
    const int wave = t >> 6, lane = t & 63;
    const int j0 = wave * 32;
    const int lr = lane & 15;
    const int q  = lane >> 4;

    union FU { uint4 u; bf16x8 v; };

    FU wA[2][4], wB[2][4], wC[2][4];   // W12h, W12l, Wsh
    #pragma unroll
    for (int jt = 0; jt < 2; ++jt) {
        const int brow = (j0 + jt * 16 + lr) * 16 + q;
        #pragma unroll
        for (int ks = 0; ks < 4; ++ks) {
            wA[jt][ks].u = w12h4[brow + ks * 4];
            wB[jt][ks].u = w12l4[brow + ks * 4];
            wC[jt][ks].u = wsh4[brow + ks * 4];
        }
    }

#define LOAD_TILE(BX, BL, BA, BC, TILE) do {                                   \
    int row_ = (TILE) * 16 + lr; if (row_ > N - 1) row_ = N - 1;               \
    const int ar_ = row_ * 16 + q;                                             \
    _Pragma("unroll")                                                          \
    for (int ks = 0; ks < 4; ++ks) {                                           \
        BX[ks].u = xh4[ar_ + ks * 4];                                          \
        BL[ks].u = xl4[ar_ + ks * 4];                                          \
        BA[ks].u = a1h4[ar_ + ks * 4];                                         \
    }                                                                          \
    _Pragma("unroll")                                                          \
    for (int jt = 0; jt < 2; ++jt)                                             \
        _Pragma("unroll")                                                      \
        for (int r = 0; r < 4; ++r) {                                          \
            int rr_ = (TILE) * 16 + q * 4 + r; if (rr_ > N - 1) rr_ = N - 1;   \
            BC[jt * 4 + r] = a2b[(size_t)rr_ * 64 + ((j0 + jt * 16 + lr) >> 1)]; \
        }                                                                      \
} while (0)

#define COMPUTE_STORE(BX, BL, BA, BC, TILE) do {                               \
    f32x4 c_[2];                                                               \
    _Pragma("unroll")                                                          \
    for (int jt = 0; jt < 2; ++jt)                                             \
        _Pragma("unroll")                                                      \
        for (int r = 0; r < 4; ++r) {                                          \
            unsigned w_ = BC[jt * 4 + r];                                      \
            c_[jt][r] = __uint_as_float((lr & 1) ? (w_ & 0xFFFF0000u) : (w_ << 16)); \
        }                                                                      \
    _Pragma("unroll")                                                          \
    for (int jt = 0; jt < 2; ++jt)                                             \
        _Pragma("unroll")                                                      \
        for (int ks = 0; ks < 4; ++ks) {                                       \
            c_[jt] = __builtin_amdgcn_mfma_f32_16x16x32_bf16(BX[ks].v, wA[jt][ks].v, c_[jt], 0, 0, 0); \
            c_[jt] = __builtin_amdgcn_mfma_f32_16x16x32_bf16(BL[ks].v, wA[jt][ks].v, c_[jt], 0, 0, 0); \
            c_[jt] = __builtin_amdgcn_mfma_f32_16x16x32_bf16(BX[ks].v, wB[jt][ks].v, c_[jt], 0, 0, 0); \
            c_[jt] = __builtin_amdgcn_mfma_f32_16x16x32_bf16(BA[ks].v, wC[jt][ks].v, c_[jt], 0, 0, 0); \
        }                                                                      \
    _Pragma("unroll")                                                          \
    for (int jt = 0; jt < 2; ++jt)                                             \
        _Pragma("unroll")                                                      \
        for (int r = 0; r < 4; ++r) {                                          \
            int rr_ = (TILE) * 16 + q * 4 + r;                                 \
            if (rr_ < N)                                                       \
                __builtin_nontemporal_store(c_[jt][r],                         \
                    &fout[(size_t)rr_ * D + j0 + jt * 16 + lr]);               \
        }                                                                      \
} while (0)

    FU Axh[4], Axl[4], Aa1[4]; unsigned Aci[8];
    FU Bxh[4], Bxl[4], Ba1[4]; unsigned Bci[8];

    int tile = blockIdx.x;
    const int step = gridDim.x;
    if (tile >= nTiles) return;
    LOAD_TILE(Axh, Axl, Aa1, Aci, tile);
    while (true) {
        int tn = tile + step;
        if (tn < nTiles) LOAD_TILE(Bxh, Bxl, Ba1, Bci, tn);
        COMPUTE_STORE(Axh, Axl, Aa1, Aci, tile);
        tile = tn;
        if (tile >= nTiles) break;
        tn = tile + step;
        if (tn < nTiles) LOAD_TILE(Axh, Axl, Aa1, Aci, tn);
        COMPUTE_STORE(Bxh, Bxl, Ba1, Bci, tile);
        tile = tn;
        if (tile >= nTiles) break;
    }
#undef LOAD_TILE
#undef COMPUTE_STORE
}

extern "C" void kernel_launch(void* const* d_in, const int* in_sizes, int n_in,
                              void* d_out, int out_size, void* d_ws, size_t ws_size,
                              hipStream_t stream) {
    const float* x        = (const float*)d_in[0];
    const int*   ei       = (const int*)d_in[1];    // [2, E] flat
    const float* ew       = (const float*)d_in[2];
    const float* Wr1      = (const float*)d_in[3];
    const float* Wr2      = (const float*)d_in[4];
    const int*   cell_len = (const int*)d_in[5];

    const int N = in_sizes[0] / D;      // 50000
    const int E = in_sizes[1] / 2;      // 800000
    const int* src = ei;
    const int* dst = ei + E;

    // workspace layout (~77MB of the ws)
    char* ws = (char*)d_ws;
    size_t off = 0;
    unsigned* meta = (unsigned*)(ws + off); off += (size_t)4 * CAP * N;   // 12.8MB
    int*      cnt  = (int*)     (ws + off); off += (size_t)4 * N;
    off = (off + 255) & ~(size_t)255;
    unsigned* xh   = (unsigned*)(ws + off); off += (size_t)2 * N * D;     // bf16-hi x
    unsigned* xl   = (unsigned*)(ws + off); off += (size_t)2 * N * D;     // bf16-lo x
    unsigned* a1h  = (unsigned*)(ws + off); off += (size_t)2 * N * D;     // bf16 A1
    unsigned* a2b  = (unsigned*)(ws + off); off += (size_t)2 * N * D;     // bf16 A2
    unsigned* xq   = (unsigned*)(ws + off); off += (size_t)1 * N * D;     // fp8 x
    unsigned* a1q  = (unsigned*)(ws + off); off += (size_t)1 * N * D;     // fp8 A1
    unsigned* wsh  = (unsigned*)(ws + off); off += (size_t)2 * D * D;
    unsigned* w12h = (unsigned*)(ws + off); off += (size_t)2 * D * D;
    unsigned* w12l = (unsigned*)(ws + off); off += (size_t)2 * D * D;
    if (ws_size < off) return;
    float* out = (float*)d_out;

    hipMemsetAsync(cnt, 0, (size_t)4 * N, stream);

    const int sliceLen = (N + NSLICE - 1) / NSLICE;                  // 6250
    const int nFill  = ((E + 2047) / 2048) * NSLICE;                 // 3128
    const int xvec   = N * D / 4;                                    // 1.6M
    const int nSplit = (xvec + 255) / 256;                           // 6250
    const int nW     = (D * 64 + 255) / 256;                         // 32
    const int aggBlocks = (N + 3) / 4;
    const int nTiles = (N + 15) / 16;                                // 3125

    // fused preprocessing: fill | split | wcombine (independent roles)
    k_pre<<<nFill + nSplit + nW, 256, 0, stream>>>(
        src, dst, ew, cell_len, cnt, meta, E, sliceLen, nFill,
        x, (uint2*)xh, (uint2*)xl, xq, xvec, nSplit,
        Wr1, Wr2, wsh, w12h, w12l);

    // A1 = mean-agg(x_fp8)  [bf16 + fp8];  A2 = mean-agg(A1_fp8)  [bf16]
    k_agg_fp8<true ><<<aggBlocks, 256, 0, stream>>>(
        (const unsigned short*)xq, (const uint4*)meta, cnt,
        a1h, (unsigned short*)a1q, N);
    k_agg_fp8<false><<<aggBlocks, 256, 0, stream>>>(
        (const unsigned short*)a1q, (const uint4*)meta, cnt,
        a2b, nullptr, N);

    // out = A2 + A1 @ (W1+W2)^T + x @ (W2@W1)^T   (persistent, pipelined)
    k_gemm2<<<GEMM_BLOCKS, 256, 0, stream>>>((const uint4*)xh, (const uint4*)xl,
                                             (const uint4*)a1h,
                                             (const uint4*)w12h, (const uint4*)w12l,
                                             (const uint4*)wsh, a2b, out, N, nTiles);
}

// Round 6
// 210.602 us; speedup vs baseline: 1.0945x; 1.0945x over previous
//
#include <hip/hip_runtime.h>
#include <cstdint>
#include <cstddef>

#define D 128
#define SAME_W 0.3f
#define CROSS_W 1.0f
#define NSLICE 8    // dst slices ~ XCDs (blockIdx%8 heuristic)
#define CAP 64      // bucket capacity: degree ~ Poisson(16), P(any >= 64) ~ 1e-14
#define GEMM_BLOCKS 1024  // 4 blocks/CU possible at VGPR=128 (grid was the cap;
                          // launch_bounds(,4) spills — R3)

using bf16x8 = __attribute__((ext_vector_type(8))) __bf16;
using f32x4  = __attribute__((ext_vector_type(4))) float;
using i32x4  = __attribute__((ext_vector_type(4))) int;
using u32x4  = __attribute__((ext_vector_type(4))) unsigned;

__device__ __forceinline__ unsigned bf16rne(float f) {
    unsigned u = __float_as_uint(f);
    return (u + 0x7FFFu + ((u >> 16) & 1u)) >> 16;   // round-to-nearest-even
}

// ============ fused preprocessing: fill | x-split | W-combine, one dispatch
// Fill blocks come FIRST so the blockIdx%8 -> XCD round-robin slice mapping
// is preserved.
__global__ __launch_bounds__(256) void k_pre(
    // fill
    const int* __restrict__ src, const int* __restrict__ dst,
    const float* __restrict__ ew, const int* __restrict__ cell_len,
    int* __restrict__ cnt, unsigned* __restrict__ meta, int E, int sliceLen,
    int nFill,
    // split: x -> bf16 hi/lo + packed fp8
    const float* __restrict__ xf, uint2* __restrict__ xh2,
    uint2* __restrict__ xl2, unsigned* __restrict__ xq, int nvec, int nSplit,
    // wcombine
    const float* __restrict__ W1, const float* __restrict__ W2,
    unsigned* __restrict__ wsh, unsigned* __restrict__ w12h,
    unsigned* __restrict__ w12l)
{
    const int b = blockIdx.x;
    if (b < nFill) {
        // ---- XCD-sliced capped-bucket fill. Non-temporal edge loads: the
        // streaming re-read must not evict the slice-local meta lines (1.6MB,
        // L2-resident per XCD) from L2.
        const int slice = b & (NSLICE - 1);
        const int lo = slice * sliceLen, hi = lo + sliceLen;
        const int chunk = b >> 3;                 // 2048 edges per chunk
        const int c = *cell_len;
        #pragma unroll
        for (int u = 0; u < 2; ++u) {
            const int e = chunk * 2048 + u * 1024 + (int)threadIdx.x * 4;
            if (e + 3 < E) {
                i32x4 d4 = __builtin_nontemporal_load((const i32x4*)(dst + e));
                i32x4 s4 = __builtin_nontemporal_load((const i32x4*)(src + e));
                f32x4 w4 = __builtin_nontemporal_load((const f32x4*)(ew + e));
                #pragma unroll
                for (int k = 0; k < 4; ++k) {
                    const int d = d4[k];
                    if (d >= lo && d < hi) {
                        const int   s = s4[k];
                        const float w = w4[k];
                        float wt = w * (((s > c) == (d > c)) ? SAME_W : CROSS_W);
                        int pos = atomicAdd(&cnt[d], 1);
                        if (pos < CAP)   // P(overflow) ~ 1e-14; guard for safety
                            meta[d * CAP + pos] = (unsigned)s | (bf16rne(wt) << 16);
                    }
                }
            } else {
                for (int k = 0; k < 4; ++k) {
                    const int ee = e + k;
                    if (ee < E) {
                        int d = __builtin_nontemporal_load(&dst[ee]);
                        if (d >= lo && d < hi) {
                            int s = __builtin_nontemporal_load(&src[ee]);
                            float w = __builtin_nontemporal_load(&ew[ee]);
                            float wt = w * (((s > c) == (d > c)) ? SAME_W : CROSS_W);
                            int pos = atomicAdd(&cnt[d], 1);
                            if (pos < CAP)
                                meta[d * CAP + pos] = (unsigned)s | (bf16rne(wt) << 16);
                        }
                    }
                }
            }
        }
    } else if (b < nFill + nSplit) {
        // ---- x -> split bf16 (hi+lo) + packed fp8 e4m3 (agg gather payload)
        int i = (b - nFill) * 256 + (int)threadIdx.x;
        if (i >= nvec) return;
        const f32x4* px = (const f32x4*)(xf + (size_t)i * 4);
        f32x4 v = __builtin_nontemporal_load(px);
        unsigned h0 = bf16rne(v[0]), h1 = bf16rne(v[1]),
                 h2 = bf16rne(v[2]), h3 = bf16rne(v[3]);
        xh2[i] = make_uint2(h0 | (h1 << 16), h2 | (h3 << 16));
        float r0 = v[0] - __uint_as_float(h0 << 16);
        float r1 = v[1] - __uint_as_float(h1 << 16);
        float r2 = v[2] - __uint_as_float(h2 << 16);
        float r3 = v[3] - __uint_as_float(h3 << 16);
        xl2[i] = make_uint2(bf16rne(r0) | (bf16rne(r1) << 16),
                            bf16rne(r2) | (bf16rne(r3) << 16));
        int q = __builtin_amdgcn_cvt_pk_fp8_f32(v[0], v[1], 0, false);
        q = __builtin_amdgcn_cvt_pk_fp8_f32(v[2], v[3], q, true);
        xq[i] = (unsigned)q;
    } else {
        // ---- Ws = bf16(W1+W2); W12 = split-bf16(W2 @ W1)
        // out = A2 + A1@Ws^T + x@W12^T (agg commutes with right-mul)
        int t = (b - nFill - nSplit) * 256 + threadIdx.x;
        int j = t >> 6, kp = t & 63;
        int k0 = kp * 2;
        float d0 = 0.f, d1 = 0.f;
        #pragma unroll 4
        for (int m = 0; m < D; ++m) {
            float a = W2[j * D + m];
            d0 = fmaf(a, W1[m * D + k0], d0);
            d1 = fmaf(a, W1[m * D + k0 + 1], d1);
        }
        float s0 = W1[j * D + k0] + W2[j * D + k0];
        float s1 = W1[j * D + k0 + 1] + W2[j * D + k0 + 1];
        wsh[j * 64 + kp] = bf16rne(s0) | (bf16rne(s1) << 16);
        unsigned h0 = bf16rne(d0), h1 = bf16rne(d1);
        w12h[j * 64 + kp] = h0 | (h1 << 16);
        float r0 = d0 - __uint_as_float(h0 << 16);
        float r1 = d1 - __uint_as_float(h1 << 16);
        w12l[j * 64 + kp] = bf16rne(r0) | (bf16rne(r1) << 16);
    }
}

// ---------------- gather + scatter-free mean over capped buckets, fp8 payload
// TWO nodes per wave: half-wave (32 lanes x 4B uint = same 128B/row coalesced
// gather) per node. Doubles in-flight row-gathers per wave (~32 vs ~16) and
// halves wave count — H1 latency-bound test; byte traffic unchanged (H2
// fabric-bound null). Entries past a half's own cn are neutralized (v->0,
// wt->0; fp8 garbage can decode NaN, and NaN*0 = NaN, so zero the VALUE too).
template <bool EMIT_FP8>
__global__ __launch_bounds__(256) void k_agg_fp8(const unsigned* __restrict__ xq32,
                                                 const unsigned* __restrict__ meta,
                                                 const int* __restrict__ cnt,
                                                 uint2* __restrict__ outb2,
                                                 unsigned* __restrict__ outq32,
                                                 int N) {
    int gid = blockIdx.x * blockDim.x + threadIdx.x;
    int wid  = gid >> 6;
    int lane = gid & 63;
    int half = lane >> 5, lh = lane & 31;
    int node = wid * 2 + half;
    bool alive = node < N;
    int nodeC = alive ? node : N - 1;
    const int cn0 = cnt[nodeC];
    int cn = alive ? min(cn0, CAP) : 0;
    int cnW = max(cn, __shfl_xor(cn, 32));   // wave-uniform loop bound
    const unsigned* mrow = meta + (size_t)nodeC * CAP;
    float a0 = 0.f, a1 = 0.f, a2 = 0.f, a3 = 0.f;
    int i = 0;
    #pragma unroll 1
    for (; i + 16 <= cnW; i += 16) {
        uint4 mq[4];
        #pragma unroll
        for (int u2 = 0; u2 < 4; ++u2) mq[u2] = ((const uint4*)mrow)[(i >> 2) + u2];
        unsigned v[16];
        #pragma unroll
        for (int u = 0; u < 16; ++u) {
            unsigned m = ((const unsigned*)mq)[u];
            v[u] = xq32[(size_t)(m & 0xFFFFu) * 32 + lh];
        }
        #pragma unroll
        for (int u = 0; u < 16; ++u) {
            unsigned m = ((const unsigned*)mq)[u];
            bool ok = (i + u) < cn;
            unsigned vv = ok ? v[u] : 0u;
            float wt = ok ? __uint_as_float(m & 0xFFFF0000u) : 0.0f;
            a0 = fmaf(__builtin_amdgcn_cvt_f32_fp8(vv, 0), wt, a0);
            a1 = fmaf(__builtin_amdgcn_cvt_f32_fp8(vv, 1), wt, a1);
            a2 = fmaf(__builtin_amdgcn_cvt_f32_fp8(vv, 2), wt, a2);
            a3 = fmaf(__builtin_amdgcn_cvt_f32_fp8(vv, 3), wt, a3);
        }
    }
    #pragma unroll 1
    for (; i + 4 <= cnW; i += 4) {
        uint4 mq = ((const uint4*)mrow)[i >> 2];
        unsigned v[4];
        #pragma unroll
        for (int u = 0; u < 4; ++u)
            v[u] = xq32[(size_t)(((const unsigned*)&mq)[u] & 0xFFFFu) * 32 + lh];
        #pragma unroll
        for (int u = 0; u < 4; ++u) {
            unsigned m = ((const unsigned*)&mq)[u];
            bool ok = (i + u) < cn;
            unsigned vv = ok ? v[u] : 0u;
            float wt = ok ? __uint_as_float(m & 0xFFFF0000u) : 0.0f;
            a0 = fmaf(__builtin_amdgcn_cvt_f32_fp8(vv, 0), wt, a0);
            a1 = fmaf(__builtin_amdgcn_cvt_f32_fp8(vv, 1), wt, a1);
            a2 = fmaf(__builtin_amdgcn_cvt_f32_fp8(vv, 2), wt, a2);
            a3 = fmaf(__builtin_amdgcn_cvt_f32_fp8(vv, 3), wt, a3);
        }
    }
    for (; i < cnW; ++i) {
        unsigned m = mrow[i];
        unsigned v = xq32[(size_t)(m & 0xFFFFu) * 32 + lh];
        bool ok = i < cn;
        unsigned vv = ok ? v : 0u;
        float wt = ok ? __uint_as_float(m & 0xFFFF0000u) : 0.0f;
        a0 = fmaf(__builtin_amdgcn_cvt_f32_fp8(vv, 0), wt, a0);
        a1 = fmaf(__builtin_amdgcn_cvt_f32_fp8(vv, 1), wt, a1);
        a2 = fmaf(__builtin_amdgcn_cvt_f32_fp8(vv, 2), wt, a2);
        a3 = fmaf(__builtin_amdgcn_cvt_f32_fp8(vv, 3), wt, a3);
    }
    if (alive) {
        const float s = 1.0f / (float)max(cn0, 1);
        float r0 = a0 * s, r1 = a1 * s, r2 = a2 * s, r3 = a3 * s;
        uint2 w;
        w.x = bf16rne(r0) | (bf16rne(r1) << 16);
        w.y = bf16rne(r2) | (bf16rne(r3) << 16);
        outb2[(size_t)node * 32 + lh] = w;
        if (EMIT_FP8) {
            int q = __builtin_amdgcn_cvt_pk_fp8_f32(r0, r1, 0, false);
            q = __builtin_amdgcn_cvt_pk_fp8_f32(r2, r3, q, true);
            outq32[(size_t)node * 32 + lh] = (unsigned)q;
        }
    }
}

// -------------- fused final GEMM: out = A2 + A1 @ Ws^T + x @ W12^T (split x)
// bf16 xh/xl loads (96B/lane-row, no cvt on the load->MFMA path).
// Persistent grid of 1024 (4 blocks/CU at VGPR=128; launch_bounds(256,2) keeps
// the allocator at 128 — min-waves=4 spills, R3). Two A-fragment buffers
// ping-pong so tile t+1's loads fly during tile t's MFMAs.
__global__ __launch_bounds__(256, 2) void k_gemm2(
    const uint4* __restrict__ xh4, const uint4* __restrict__ xl4,   // [N][16]
    const uint4* __restrict__ a1h4,                                 // [N][16]
    const uint4* __restrict__ w12h4, const uint4* __restrict__ w12l4,
    const uint4* __restrict__ wsh4,                                 // [128][16]
    const unsigned* __restrict__ a2b,                               // [N][64] bf16x2
    float* __restrict__ fout, int N, int nTiles)
{
    const int t = threadIdx.x;
    const int wave = t >> 6, lane = t & 63;
    const int j0 = wave * 32;
    const int lr = lane & 15;
    const int q  = lane >> 4;

    union FU { uint4 u; bf16x8 v; };

    FU wA[2][4], wB[2][4], wC[2][4];   // W12h, W12l, Wsh
    #pragma unroll
    for (int jt = 0; jt < 2; ++jt) {
        const int brow = (j0 + jt * 16 + lr) * 16 + q;
        #pragma unroll
        for (int ks = 0; ks < 4; ++ks) {
            wA[jt][ks].u = w12h4[brow + ks * 4];
            wB[jt][ks].u = w12l4[brow + ks * 4];
            wC[jt][ks].u = wsh4[brow + ks * 4];
        }
    }

#define LOAD_TILE(BX, BL, BA, BC, TILE) do {                                   \
    int row_ = (TILE) * 16 + lr; if (row_ > N - 1) row_ = N - 1;               \
    const int ar_ = row_ * 16 + q;                                             \
    _Pragma("unroll")                                                          \
    for (int ks = 0; ks < 4; ++ks) {                                           \
        BX[ks].u = xh4[ar_ + ks * 4];                                          \
        BL[ks].u = xl4[ar_ + ks * 4];                                          \
        BA[ks].u = a1h4[ar_ + ks * 4];                                         \
    }                                                                          \
    _Pragma("unroll")                                                          \
    for (int jt = 0; jt < 2; ++jt)                                             \
        _Pragma("unroll")                                                      \
        for (int r = 0; r < 4; ++r) {                                          \
            int rr_ = (TILE) * 16 + q * 4 + r; if (rr_ > N - 1) rr_ = N - 1;   \
            BC[jt * 4 + r] = a2b[(size_t)rr_ * 64 + ((j0 + jt * 16 + lr) >> 1)]; \
        }                                                                      \
} while (0)

#define COMPUTE_STORE(BX, BL, BA, BC, TILE) do {                               \
    f32x4 c_[2];                                                               \
    _Pragma("unroll")                                                          \
    for (int jt = 0; jt < 2; ++jt)                                             \
        _Pragma("unroll")                                                      \
        for (int r = 0; r < 4; ++r) {                                          \
            unsigned w_ = BC[jt * 4 + r];                                      \
            c_[jt][r] = __uint_as_float((lr & 1) ? (w_ & 0xFFFF0000u) : (w_ << 16)); \
        }                                                                      \
    _Pragma("unroll")                                                          \
    for (int jt = 0; jt < 2; ++jt)                                             \
        _Pragma("unroll")                                                      \
        for (int ks = 0; ks < 4; ++ks) {                                       \
            c_[jt] = __builtin_amdgcn_mfma_f32_16x16x32_bf16(BX[ks].v, wA[jt][ks].v, c_[jt], 0, 0, 0); \
            c_[jt] = __builtin_amdgcn_mfma_f32_16x16x32_bf16(BL[ks].v, wA[jt][ks].v, c_[jt], 0, 0, 0); \
            c_[jt] = __builtin_amdgcn_mfma_f32_16x16x32_bf16(BX[ks].v, wB[jt][ks].v, c_[jt], 0, 0, 0); \
            c_[jt] = __builtin_amdgcn_mfma_f32_16x16x32_bf16(BA[ks].v, wC[jt][ks].v, c_[jt], 0, 0, 0); \
        }                                                                      \
    _Pragma("unroll")                                                          \
    for (int jt = 0; jt < 2; ++jt)                                             \
        _Pragma("unroll")                                                      \
        for (int r = 0; r < 4; ++r) {                                          \
            int rr_ = (TILE) * 16 + q * 4 + r;                                 \
            if (rr_ < N)                                                       \
                __builtin_nontemporal_store(c_[jt][r],                         \
                    &fout[(size_t)rr_ * D + j0 + jt * 16 + lr]);               \
        }                                                                      \
} while (0)

    FU Axh[4], Axl[4], Aa1[4]; unsigned Aci[8];
    FU Bxh[4], Bxl[4], Ba1[4]; unsigned Bci[8];

    int tile = blockIdx.x;
    const int step = gridDim.x;
    if (tile >= nTiles) return;
    LOAD_TILE(Axh, Axl, Aa1, Aci, tile);
    while (true) {
        int tn = tile + step;
        if (tn < nTiles) LOAD_TILE(Bxh, Bxl, Ba1, Bci, tn);
        COMPUTE_STORE(Axh, Axl, Aa1, Aci, tile);
        tile = tn;
        if (tile >= nTiles) break;
        tn = tile + step;
        if (tn < nTiles) LOAD_TILE(Axh, Axl, Aa1, Aci, tn);
        COMPUTE_STORE(Bxh, Bxl, Ba1, Bci, tile);
        tile = tn;
        if (tile >= nTiles) break;
    }
#undef LOAD_TILE
#undef COMPUTE_STORE
}

extern "C" void kernel_launch(void* const* d_in, const int* in_sizes, int n_in,
                              void* d_out, int out_size, void* d_ws, size_t ws_size,
                              hipStream_t stream) {
    const float* x        = (const float*)d_in[0];
    const int*   ei       = (const int*)d_in[1];    // [2, E] flat
    const float* ew       = (const float*)d_in[2];
    const float* Wr1      = (const float*)d_in[3];
    const float* Wr2      = (const float*)d_in[4];
    const int*   cell_len = (const int*)d_in[5];

    const int N = in_sizes[0] / D;      // 50000
    const int E = in_sizes[1] / 2;      // 800000
    const int* src = ei;
    const int* dst = ei + E;

    // workspace layout (~77MB of the ws)
    char* ws = (char*)d_ws;
    size_t off = 0;
    unsigned* meta = (unsigned*)(ws + off); off += (size_t)4 * CAP * N;   // 12.8MB
    int*      cnt  = (int*)     (ws + off); off += (size_t)4 * N;
    off = (off + 255) & ~(size_t)255;
    unsigned* xh   = (unsigned*)(ws + off); off += (size_t)2 * N * D;     // bf16-hi x
    unsigned* xl   = (unsigned*)(ws + off); off += (size_t)2 * N * D;     // bf16-lo x
    unsigned* a1h  = (unsigned*)(ws + off); off += (size_t)2 * N * D;     // bf16 A1
    unsigned* a2b  = (unsigned*)(ws + off); off += (size_t)2 * N * D;     // bf16 A2
    unsigned* xq   = (unsigned*)(ws + off); off += (size_t)1 * N * D;     // fp8 x
    unsigned* a1q  = (unsigned*)(ws + off); off += (size_t)1 * N * D;     // fp8 A1
    unsigned* wsh  = (unsigned*)(ws + off); off += (size_t)2 * D * D;
    unsigned* w12h = (unsigned*)(ws + off); off += (size_t)2 * D * D;
    unsigned* w12l = (unsigned*)(ws + off); off += (size_t)2 * D * D;
    if (ws_size < off) return;
    float* out = (float*)d_out;

    hipMemsetAsync(cnt, 0, (size_t)4 * N, stream);

    const int sliceLen = (N + NSLICE - 1) / NSLICE;                  // 6250
    const int nFill  = ((E + 2047) / 2048) * NSLICE;                 // 3128
    const int xvec   = N * D / 4;                                    // 1.6M
    const int nSplit = (xvec + 255) / 256;                           // 6250
    const int nW     = (D * 64 + 255) / 256;                         // 32
    const int nWaves = (N + 1) / 2;                                  // 2 nodes/wave
    const int aggBlocks = (nWaves * 64 + 255) / 256;                 // 6250
    const int nTiles = (N + 15) / 16;                                // 3125

    // fused preprocessing: fill | split | wcombine (independent roles)
    k_pre<<<nFill + nSplit + nW, 256, 0, stream>>>(
        src, dst, ew, cell_len, cnt, meta, E, sliceLen, nFill,
        x, (uint2*)xh, (uint2*)xl, xq, xvec, nSplit,
        Wr1, Wr2, wsh, w12h, w12l);

    // A1 = mean-agg(x_fp8)  [bf16 + fp8];  A2 = mean-agg(A1_fp8)  [bf16]
    k_agg_fp8<true ><<<aggBlocks, 256, 0, stream>>>(
        xq, meta, cnt, (uint2*)a1h, a1q, N);
    k_agg_fp8<false><<<aggBlocks, 256, 0, stream>>>(
        a1q, meta, cnt, (uint2*)a2b, nullptr, N);

    // out = A2 + A1 @ (W1+W2)^T + x @ (W2@W1)^T   (persistent, pipelined)
    k_gemm2<<<GEMM_BLOCKS, 256, 0, stream>>>((const uint4*)xh, (const uint4*)xl,
                                             (const uint4*)a1h,
                                             (const uint4*)w12h, (const uint4*)w12l,
                                             (const uint4*)wsh, a2b, out, N, nTiles);
}